// Round 11
// baseline (179.195 us; speedup 1.0000x reference)
//
#include <hip/hip_runtime.h>
#include <math.h>

#define Bsz 4096
#define Ssz 200
#define Dsz 64
#define NK  5
#define NT  512
#define ROWH 72   // halves per emb row in LDS (144 B): b128-aligned, bank-balanced

typedef _Float16 half_t;
typedef _Float16 h2 __attribute__((ext_vector_type(2)));

__device__ inline h2 shfl_xor_h2(h2 v, int m) {
    int iv = __builtin_bit_cast(int, v);
    iv = __shfl_xor(iv, m);
    return __builtin_bit_cast(h2, iv);
}

__device__ inline h2 pk(float a, float b) {
    return __builtin_bit_cast(h2, __builtin_amdgcn_cvt_pkrtz(a, b));
}

__device__ inline float fdot2(h2 a, h2 b, float c) {
#if __has_builtin(__builtin_amdgcn_fdot2)
    return __builtin_amdgcn_fdot2(a, b, c, false);
#else
    return c + (float)a.x * (float)b.x + (float)a.y * (float)b.y;
#endif
}

__device__ inline float fast_tanh(float x) {
    float e = __expf(-2.0f * fabsf(x));
    float r = (1.0f - e) / (1.0f + e);
    return copysignf(r, x);
}

__global__ void zero_loss_kernel(float* loss) {
    if (threadIdx.x == 0) *loss = 0.0f;
}

__global__ __launch_bounds__(NT, 8) void tan_kernel(
    const int* __restrict__ x, const float* __restrict__ y,
    const float* __restrict__ emb_table,
    const float* __restrict__ att_w, const float* __restrict__ att_b,
    const float* __restrict__ W0, const float* __restrict__ W1,
    const float* __restrict__ W2, const float* __restrict__ W3,
    const float* __restrict__ W4,
    float* __restrict__ out_logit, float* __restrict__ loss_out)
{
    __shared__ alignas(16) half_t embh[Ssz * ROWH];      // 28800 B
    __shared__ alignas(16) float  att[NK][Ssz];          //  4000 B (logits, then scores)
    __shared__ alignas(16) half_t urph[8][NK][Dsz];      //  5120 B
    __shared__ float wu[18];                             //    72 B
    // total ~38 KB -> 4 blocks/CU -> 32 waves/CU

    const int b   = blockIdx.x;
    const int tid = threadIdx.x;
    const int w   = tid >> 6;
    const int l   = tid & 63;

    // ---- P1: coalesced gather, 16 lanes/row, 7 chunk-loads in flight/thread ----
    {
        const int* xb = x + b * Ssz;
        float4 v[7];
#pragma unroll
        for (int p = 0; p < 7; ++p) {
            int i = tid + NT * p;
            if (i > Ssz * 16 - 1) i = Ssz * 16 - 1;
            const int s = i >> 4, c = i & 15;
            const int xi = xb[s];                 // 16-lane broadcast, L1-hot
            v[p] = ((const float4*)(emb_table + (size_t)xi * Dsz))[c];
        }
#pragma unroll
        for (int p = 0; p < 7; ++p) {
            const int i = tid + NT * p;
            if (p < 6 || i < Ssz * 16) {
                const int s = i >> 4, c = i & 15;
                h2 lo = pk(v[p].x, v[p].y);
                h2 hi = pk(v[p].z, v[p].w);
                uint2 u = { __builtin_bit_cast(unsigned, lo),
                            __builtin_bit_cast(unsigned, hi) };
                *(uint2*)(embh + s * ROWH + c * 4) = u;
            }
        }
    }
    __syncthreads();

    // ---- P1.5: attention logits via fdot2, 2 threads/row; aw from global (L1-hot) ----
    if (tid < 2 * Ssz) {
        const int s = tid >> 1, h = tid & 1;
        union { uint4 q[4]; h2 hh[16]; } ue;
        const uint4* rp = (const uint4*)(embh + s * ROWH + h * 32);
#pragma unroll
        for (int i = 0; i < 4; ++i) ue.q[i] = rp[i];
        float acc[NK];
#pragma unroll 1
        for (int k = 0; k < NK; ++k) {
            const float4* ap = (const float4*)(att_w + k * Dsz + h * 32);
            h2 ah[16];
#pragma unroll
            for (int i = 0; i < 4; ++i) {
                float4 a0 = ap[2 * i], a1 = ap[2 * i + 1];
                ah[4 * i + 0] = pk(a0.x, a0.y);
                ah[4 * i + 1] = pk(a0.z, a0.w);
                ah[4 * i + 2] = pk(a1.x, a1.y);
                ah[4 * i + 3] = pk(a1.z, a1.w);
            }
            float a = 0.f;
#pragma unroll
            for (int i = 0; i < 16; ++i) a = fdot2(ue.hh[i], ah[i], a);
            acc[k] = a;
        }
#pragma unroll
        for (int k = 0; k < NK; ++k) acc[k] += __shfl_xor(acc[k], 1);
        if (h == 0) {
#pragma unroll
            for (int k = 0; k < NK; ++k) att[k][s] = fast_tanh(acc[k] + att_b[k]);
        }
    }
    __syncthreads();

    // ---- P2: softmax over s for each k (waves 0..4) ----
    if (w < NK) {
        const int k = w;
        float vals[4];
        float mx = -1e30f;
#pragma unroll
        for (int j = 0; j < 4; ++j) {
            int s = l + 64 * j;
            vals[j] = (s < Ssz) ? att[k][s] : -1e30f;
            mx = fmaxf(mx, vals[j]);
        }
#pragma unroll
        for (int m = 32; m >= 1; m >>= 1) mx = fmaxf(mx, __shfl_xor(mx, m));
        float sum = 0.f;
#pragma unroll
        for (int j = 0; j < 4; ++j) {
            vals[j] = __expf(vals[j] - mx);
            sum += vals[j];
        }
#pragma unroll
        for (int m = 32; m >= 1; m >>= 1) sum += __shfl_xor(sum, m);
        float inv = 1.0f / sum;
#pragma unroll
        for (int j = 0; j < 4; ++j) {
            int s = l + 64 * j;
            if (s < Ssz) att[k][s] = vals[j] * inv;
        }
    }
    __syncthreads();

    // ---- P3: user_rep, packed-fp16; thread (c=tid&7, j=tid>>3), s = j + 64t ----
    {
        const int c = tid & 7;           // d-frag [c*8, c*8+8)
        const int j = tid >> 3;          // 64 s-groups
        h2 acc[NK][4];
#pragma unroll
        for (int k = 0; k < NK; ++k)
#pragma unroll
            for (int i = 0; i < 4; ++i) acc[k][i] = (h2){(half_t)0, (half_t)0};
#pragma unroll
        for (int t = 0; t < 4; ++t) {
            const int s = j + 64 * t;
            if (s < Ssz) {
                union { uint4 q; h2 hh[4]; } u;
                u.q = *(const uint4*)(embh + s * ROWH + c * 8);
#pragma unroll
                for (int k = 0; k < NK; ++k) {
                    half_t f = (half_t)att[k][s];
                    h2 sc = (h2){f, f};
#pragma unroll
                    for (int i = 0; i < 4; ++i) acc[k][i] += u.hh[i] * sc;
                }
            }
        }
        // reduce across the 8 j's within this wave (lane bits 3,4,5)
#pragma unroll
        for (int k = 0; k < NK; ++k)
#pragma unroll
            for (int i = 0; i < 4; ++i) {
                acc[k][i] += shfl_xor_h2(acc[k][i], 8);
                acc[k][i] += shfl_xor_h2(acc[k][i], 16);
                acc[k][i] += shfl_xor_h2(acc[k][i], 32);
            }
        if (l < 8) {
#pragma unroll
            for (int k = 0; k < NK; ++k) {
                union { h2 a[4]; uint4 q; } uu;
#pragma unroll
                for (int i = 0; i < 4; ++i) uu.a[i] = acc[k][i];
                *(uint4*)(&urph[w][k][l * 8]) = uu.q;
            }
        }
    }
    __syncthreads();

    // ---- P5: W_user[j] = ur[g(j)] . W_g[r(j)] (8-partial sum folded in) ----
    for (int j = w; j < 18; j += 8) {
        const float* Wp; int g, c0;
        if      (j < 2)  { g = 0; c0 = 0;  Wp = W0; }
        else if (j < 6)  { g = 1; c0 = 2;  Wp = W1; }
        else if (j < 10) { g = 2; c0 = 6;  Wp = W2; }
        else if (j < 12) { g = 3; c0 = 10; Wp = W3; }
        else             { g = 4; c0 = 12; Wp = W4; }
        float urv = 0.f;
#pragma unroll
        for (int jj = 0; jj < 8; ++jj) urv += (float)urph[jj][g][l];
        float p = urv * Wp[(j - c0) * Dsz + l];
#pragma unroll
        for (int m = 32; m >= 1; m >>= 1) p += __shfl_xor(p, m);
        if (l == 0) wu[j] = p;
    }
    __syncthreads();

    // ---- P6: per-group softmax -> logits; CE -> atomic loss ----
    if (w == 0) {
        float lossb = 0.f;
        if (l < NK) {
            const int LEN[5] = {2, 4, 4, 2, 6};
            const int C0[5]  = {0, 2, 6, 10, 12};
            const int g = l, c0 = C0[g], len = LEN[g];
            float* op = out_logit + (size_t)b * 18;
            const float* yp = y + (size_t)b * 18;
            float mx = -1e30f;
            for (int j = 0; j < len; ++j) mx = fmaxf(mx, wu[c0 + j]);
            float sum = 0.f;
            for (int j = 0; j < len; ++j) sum += __expf(wu[c0 + j] - mx);
            float inv = 1.0f / sum;
            float lse = mx + __logf(sum);
            for (int j = 0; j < len; ++j) {
                op[c0 + j] = __expf(wu[c0 + j] - mx) * inv;
                lossb += (lse - wu[c0 + j]) * yp[c0 + j];
            }
        }
#pragma unroll
        for (int m = 1; m <= 4; m <<= 1) lossb += __shfl_xor(lossb, m);
        if (l == 0) atomicAdd(loss_out, lossb * (1.0f / Bsz));
    }
}

extern "C" void kernel_launch(void* const* d_in, const int* in_sizes, int n_in,
                              void* d_out, int out_size, void* d_ws, size_t ws_size,
                              hipStream_t stream) {
    const int*   x   = (const int*)d_in[0];
    const float* y   = (const float*)d_in[1];
    const float* emb = (const float*)d_in[2];
    const float* aw  = (const float*)d_in[3];
    const float* ab  = (const float*)d_in[4];
    const float* W0  = (const float*)d_in[5];
    const float* W1  = (const float*)d_in[6];
    const float* W2  = (const float*)d_in[7];
    const float* W3  = (const float*)d_in[8];
    const float* W4  = (const float*)d_in[9];
    float* out  = (float*)d_out;
    float* loss = out + (size_t)Bsz * 18;

    zero_loss_kernel<<<1, 64, 0, stream>>>(loss);
    tan_kernel<<<Bsz, NT, 0, stream>>>(x, y, emb, aw, ab,
                                       W0, W1, W2, W3, W4, out, loss);
}

// Round 12
// 153.664 us; speedup vs baseline: 1.1661x; 1.1661x over previous
//
#include <hip/hip_runtime.h>
#include <math.h>

#define Bsz 4096
#define Ssz 200
#define Dsz 64
#define NK  5
#define NT  512
#define ROWH 72   // halves per emb row in LDS (144 B): b128-aligned, bank-balanced
#define SPS 104   // score-pair stride (h2 units) per k

typedef _Float16 half_t;
typedef _Float16 h2 __attribute__((ext_vector_type(2)));

__device__ inline h2 shfl_xor_h2(h2 v, int m) {
    int iv = __builtin_bit_cast(int, v);
    iv = __shfl_xor(iv, m);
    return __builtin_bit_cast(h2, iv);
}

__device__ inline h2 pk(float a, float b) {
    return __builtin_bit_cast(h2, __builtin_amdgcn_cvt_pkrtz(a, b));
}

__device__ inline float fdot2(h2 a, h2 b, float c) {
#if __has_builtin(__builtin_amdgcn_fdot2)
    return __builtin_amdgcn_fdot2(a, b, c, false);
#else
    return c + (float)a.x * (float)b.x + (float)a.y * (float)b.y;
#endif
}

__device__ inline float fast_tanh(float x) {
    float e = __expf(-2.0f * fabsf(x));
    float r = (1.0f - e) / (1.0f + e);
    return copysignf(r, x);
}

__global__ void zero_loss_kernel(float* loss) {
    if (threadIdx.x == 0) *loss = 0.0f;
}

__global__ __launch_bounds__(NT, 8) void tan_kernel(
    const int* __restrict__ x, const float* __restrict__ y,
    const float* __restrict__ emb_table,
    const float* __restrict__ att_w, const float* __restrict__ att_b,
    const float* __restrict__ W0, const float* __restrict__ W1,
    const float* __restrict__ W2, const float* __restrict__ W3,
    const float* __restrict__ W4,
    float* __restrict__ out_logit, float* __restrict__ loss_out)
{
    __shared__ alignas(16) half_t embh[Ssz * ROWH];      // 28800 B
    __shared__ alignas(16) char   ovl[8 * NK * Dsz * 2]; //  5120 B: att (P1.5/P2) then urph (P3/P5)
    __shared__ alignas(16) h2     att_h2[NK * SPS];      //  2080 B (fp16 score pairs)
    __shared__ alignas(16) h2     awh[NK * 32];          //   640 B (att_w as h2)
    __shared__ alignas(16) int    xs[Ssz];               //   800 B
    __shared__ float wu[18];                             //    72 B
    // total ~37.5 KB -> 4 blocks/CU -> 32 waves/CU

    float*  att  = (float*)ovl;                          // att[k*Ssz + s], dead after P2
    half_t (*urph)[NK][Dsz] = (half_t(*)[NK][Dsz])ovl;   // [8][5][64], live from P3

    const int b   = blockIdx.x;
    const int tid = threadIdx.x;
    const int w   = tid >> 6;
    const int l   = tid & 63;

    // ---- P0: stage x indices (threads 0..199) + att_w->h2 (threads 256..415) ----
    if (tid < Ssz) xs[tid] = x[b * Ssz + tid];
    if (tid >= 256 && tid < 256 + NK * 32) {
        const int t = tid - 256;
        awh[t] = (h2){(half_t)att_w[2 * t], (half_t)att_w[2 * t + 1]};
    }
    __syncthreads();

    // ---- P1: coalesced gather, 16 lanes/row, 7 chunk-loads in flight/thread ----
    {
        float4 v[7];
#pragma unroll
        for (int p = 0; p < 7; ++p) {
            int i = tid + NT * p;
            if (i > Ssz * 16 - 1) i = Ssz * 16 - 1;
            const int s = i >> 4, c = i & 15;
            v[p] = ((const float4*)(emb_table + (size_t)xs[s] * Dsz))[c];
        }
#pragma unroll
        for (int p = 0; p < 7; ++p) {
            const int i = tid + NT * p;
            if (p < 6 || i < Ssz * 16) {
                const int s = i >> 4, c = i & 15;
                h2 lo = pk(v[p].x, v[p].y);
                h2 hi = pk(v[p].z, v[p].w);
                uint2 u = { __builtin_bit_cast(unsigned, lo),
                            __builtin_bit_cast(unsigned, hi) };
                *(uint2*)(embh + s * ROWH + c * 4) = u;
            }
        }
    }
    __syncthreads();

    // ---- P1.5: attention logits via fdot2, 2 threads/row; aw from LDS ----
    if (tid < 2 * Ssz) {
        const int s = tid >> 1, h = tid & 1;
        union { uint4 q[4]; h2 hh[16]; } ue;
        const uint4* rp = (const uint4*)(embh + s * ROWH + h * 32);
#pragma unroll
        for (int i = 0; i < 4; ++i) ue.q[i] = rp[i];
        float acc[NK];
#pragma unroll 1
        for (int k = 0; k < NK; ++k) {
            union { uint4 q[4]; h2 hh[16]; } ua;
            const uint4* ap = (const uint4*)(awh + k * 32 + h * 16);
#pragma unroll
            for (int i = 0; i < 4; ++i) ua.q[i] = ap[i];
            float a = 0.f;
#pragma unroll
            for (int i = 0; i < 16; ++i) a = fdot2(ue.hh[i], ua.hh[i], a);
            acc[k] = a;
        }
#pragma unroll
        for (int k = 0; k < NK; ++k) acc[k] += __shfl_xor(acc[k], 1);
        if (h == 0) {
#pragma unroll
            for (int k = 0; k < NK; ++k)
                att[k * Ssz + s] = fast_tanh(acc[k] + att_b[k]);
        }
    }
    __syncthreads();

    // ---- P2: softmax over s per k (waves 0..4); scores -> fp16 pairs ----
    if (w < NK) {
        const int k = w;
        float vals[4];
        float mx = -1e30f;
#pragma unroll
        for (int j = 0; j < 4; ++j) {
            int s = l + 64 * j;
            vals[j] = (s < Ssz) ? att[k * Ssz + s] : -1e30f;
            mx = fmaxf(mx, vals[j]);
        }
#pragma unroll
        for (int m = 32; m >= 1; m >>= 1) mx = fmaxf(mx, __shfl_xor(mx, m));
        float sum = 0.f;
#pragma unroll
        for (int j = 0; j < 4; ++j) {
            vals[j] = __expf(vals[j] - mx);
            sum += vals[j];
        }
#pragma unroll
        for (int m = 32; m >= 1; m >>= 1) sum += __shfl_xor(sum, m);
        float inv = 1.0f / sum;
#pragma unroll
        for (int j = 0; j < 4; ++j) {
            const int s = l + 64 * j;
            float scv = vals[j] * inv;
            float pnr = __shfl_xor(scv, 1);         // lane pair (s, s+1)
            if (s < Ssz && (l & 1) == 0)
                att_h2[k * SPS + (s >> 1)] = pk(scv, pnr);
        }
    }
    __syncthreads();   // att (fp32) dead; ovl becomes urph

    // ---- P3: user_rep; thread (c=tid&15 -> b64 d-frag, j=tid>>4 -> s-pair group) ----
    {
        const int c = tid & 15;          // d-halves [4c, 4c+4)
        const int j = tid >> 4;          // 0..31; pairs p = j + 32t
        h2 acc[NK][2];
#pragma unroll
        for (int k = 0; k < NK; ++k) {
            acc[k][0] = (h2){(half_t)0, (half_t)0};
            acc[k][1] = (h2){(half_t)0, (half_t)0};
        }
#pragma unroll
        for (int t = 0; t < 4; ++t) {
            const int p = j + 32 * t;
            if (p < 100) {
                const int s0 = 2 * p;
                union { uint2 q; h2 hh[2]; } e0, e1;
                e0.q = *(const uint2*)(embh + s0 * ROWH + c * 4);
                e1.q = *(const uint2*)(embh + (s0 + 1) * ROWH + c * 4);
#pragma unroll
                for (int k = 0; k < NK; ++k) {
                    h2 sp = att_h2[k * SPS + p];     // (score_s0, score_s0+1)
                    h2 sc0 = (h2){sp.x, sp.x};
                    h2 sc1 = (h2){sp.y, sp.y};
                    acc[k][0] += e0.hh[0] * sc0;
                    acc[k][1] += e0.hh[1] * sc0;
                    acc[k][0] += e1.hh[0] * sc1;
                    acc[k][1] += e1.hh[1] * sc1;
                }
            }
        }
        // reduce the wave's 4 j-groups (lane bits 4,5) -- 2 levels only
#pragma unroll
        for (int k = 0; k < NK; ++k)
#pragma unroll
            for (int i = 0; i < 2; ++i) {
                acc[k][i] += shfl_xor_h2(acc[k][i], 16);
                acc[k][i] += shfl_xor_h2(acc[k][i], 32);
            }
        if (l < 16) {
#pragma unroll
            for (int k = 0; k < NK; ++k) {
                union { h2 a[2]; uint2 q; } uu;
                uu.a[0] = acc[k][0]; uu.a[1] = acc[k][1];
                *(uint2*)(&urph[w][k][l * 4]) = uu.q;
            }
        }
    }
    __syncthreads();

    // ---- P5: W_user[j] = ur[g(j)] . W_g[r(j)] (8-partial sum folded in) ----
    for (int j = w; j < 18; j += 8) {
        const float* Wp; int g, c0;
        if      (j < 2)  { g = 0; c0 = 0;  Wp = W0; }
        else if (j < 6)  { g = 1; c0 = 2;  Wp = W1; }
        else if (j < 10) { g = 2; c0 = 6;  Wp = W2; }
        else if (j < 12) { g = 3; c0 = 10; Wp = W3; }
        else             { g = 4; c0 = 12; Wp = W4; }
        float urv = 0.f;
#pragma unroll
        for (int jj = 0; jj < 8; ++jj) urv += (float)urph[jj][g][l];
        float p = urv * Wp[(j - c0) * Dsz + l];
#pragma unroll
        for (int m = 32; m >= 1; m >>= 1) p += __shfl_xor(p, m);
        if (l == 0) wu[j] = p;
    }
    __syncthreads();

    // ---- P6: per-group softmax -> logits; CE -> atomic loss ----
    if (w == 0) {
        float lossb = 0.f;
        if (l < NK) {
            const int LEN[5] = {2, 4, 4, 2, 6};
            const int C0[5]  = {0, 2, 6, 10, 12};
            const int g = l, c0 = C0[g], len = LEN[g];
            float* op = out_logit + (size_t)b * 18;
            const float* yp = y + (size_t)b * 18;
            float mx = -1e30f;
            for (int j = 0; j < len; ++j) mx = fmaxf(mx, wu[c0 + j]);
            float sum = 0.f;
            for (int j = 0; j < len; ++j) sum += __expf(wu[c0 + j] - mx);
            float inv = 1.0f / sum;
            float lse = mx + __logf(sum);
            for (int j = 0; j < len; ++j) {
                op[c0 + j] = __expf(wu[c0 + j] - mx) * inv;
                lossb += (lse - wu[c0 + j]) * yp[c0 + j];
            }
        }
#pragma unroll
        for (int m = 1; m <= 4; m <<= 1) lossb += __shfl_xor(lossb, m);
        if (l == 0) atomicAdd(loss_out, lossb * (1.0f / Bsz));
    }
}

extern "C" void kernel_launch(void* const* d_in, const int* in_sizes, int n_in,
                              void* d_out, int out_size, void* d_ws, size_t ws_size,
                              hipStream_t stream) {
    const int*   x   = (const int*)d_in[0];
    const float* y   = (const float*)d_in[1];
    const float* emb = (const float*)d_in[2];
    const float* aw  = (const float*)d_in[3];
    const float* ab  = (const float*)d_in[4];
    const float* W0  = (const float*)d_in[5];
    const float* W1  = (const float*)d_in[6];
    const float* W2  = (const float*)d_in[7];
    const float* W3  = (const float*)d_in[8];
    const float* W4  = (const float*)d_in[9];
    float* out  = (float*)d_out;
    float* loss = out + (size_t)Bsz * 18;

    zero_loss_kernel<<<1, 64, 0, stream>>>(loss);
    tan_kernel<<<Bsz, NT, 0, stream>>>(x, y, emb, aw, ab,
                                       W0, W1, W2, W3, W4, out, loss);
}

// Round 13
// 153.458 us; speedup vs baseline: 1.1677x; 1.0013x over previous
//
#include <hip/hip_runtime.h>
#include <math.h>

#define Bsz 4096
#define Ssz 200
#define Dsz 64
#define NK  5
#define NT  512
#define ROWH 72   // halves per emb row in LDS (144 B): b128-aligned, bank-balanced

typedef _Float16 half_t;
typedef _Float16 h2 __attribute__((ext_vector_type(2)));

__device__ inline h2 shfl_xor_h2(h2 v, int m) {
    int iv = __builtin_bit_cast(int, v);
    iv = __shfl_xor(iv, m);
    return __builtin_bit_cast(h2, iv);
}

__device__ inline h2 pk(float a, float b) {
    return __builtin_bit_cast(h2, __builtin_amdgcn_cvt_pkrtz(a, b));
}

__device__ inline float fdot2(h2 a, h2 b, float c) {
#if __has_builtin(__builtin_amdgcn_fdot2)
    return __builtin_amdgcn_fdot2(a, b, c, false);
#else
    return c + (float)a.x * (float)b.x + (float)a.y * (float)b.y;
#endif
}

__device__ inline float fast_tanh(float x) {
    float e = __expf(-2.0f * fabsf(x));
    float r = (1.0f - e) / (1.0f + e);
    return copysignf(r, x);
}

__global__ void zero_loss_kernel(float* loss) {
    if (threadIdx.x == 0) *loss = 0.0f;
}

__global__ __launch_bounds__(NT, 8) void tan_kernel(
    const int* __restrict__ x, const float* __restrict__ y,
    const float* __restrict__ emb_table,
    const float* __restrict__ att_w, const float* __restrict__ att_b,
    const float* __restrict__ W0, const float* __restrict__ W1,
    const float* __restrict__ W2, const float* __restrict__ W3,
    const float* __restrict__ W4,
    float* __restrict__ out_logit, float* __restrict__ loss_out)
{
    __shared__ alignas(16) half_t embh[Ssz * ROWH];      // 28800 B
    __shared__ alignas(16) char   ovl[8 * NK * Dsz * 2]; //  5120 B: att fp32, then urph
    __shared__ alignas(16) h2     att5[100][8];          //  3200 B (pair p -> k=0..4 scores)
    __shared__ alignas(16) float  ur[NK][Dsz];           //  1280 B
    __shared__ alignas(16) h2     awh[NK * 32];          //   640 B (att_w as h2)
    __shared__ alignas(16) int    xs[Ssz];               //   800 B
    __shared__ float wu[18];                             //    72 B
    // total ~40.2 KB -> 4 blocks/CU -> 32 waves/CU

    float*  att  = (float*)ovl;                          // att[k*Ssz + s], dead after P2
    half_t (*urph)[NK][Dsz] = (half_t(*)[NK][Dsz])ovl;   // [8][5][64], live from P3

    const int b   = blockIdx.x;
    const int tid = threadIdx.x;
    const int w   = tid >> 6;
    const int l   = tid & 63;

    // ---- P0: stage x indices (threads 0..199) + att_w->h2 (threads 256..415) ----
    if (tid < Ssz) xs[tid] = x[b * Ssz + tid];
    if (tid >= 256 && tid < 256 + NK * 32) {
        const int t = tid - 256;
        awh[t] = (h2){(half_t)att_w[2 * t], (half_t)att_w[2 * t + 1]};
    }
    __syncthreads();

    // ---- P1: coalesced gather, 16 lanes/row, 7 chunk-loads in flight/thread ----
    {
        float4 v[7];
#pragma unroll
        for (int p = 0; p < 7; ++p) {
            int i = tid + NT * p;
            if (i > Ssz * 16 - 1) i = Ssz * 16 - 1;
            const int s = i >> 4, c = i & 15;
            v[p] = ((const float4*)(emb_table + (size_t)xs[s] * Dsz))[c];
        }
#pragma unroll
        for (int p = 0; p < 7; ++p) {
            const int i = tid + NT * p;
            if (p < 6 || i < Ssz * 16) {
                const int s = i >> 4, c = i & 15;
                h2 lo = pk(v[p].x, v[p].y);
                h2 hi = pk(v[p].z, v[p].w);
                uint2 u = { __builtin_bit_cast(unsigned, lo),
                            __builtin_bit_cast(unsigned, hi) };
                *(uint2*)(embh + s * ROWH + c * 4) = u;
            }
        }
    }
    __syncthreads();

    // ---- P1.5: attention logits via fdot2, 2 threads/row; aw from LDS ----
    if (tid < 2 * Ssz) {
        const int s = tid >> 1, h = tid & 1;
        union { uint4 q[4]; h2 hh[16]; } ue;
        const uint4* rp = (const uint4*)(embh + s * ROWH + h * 32);
#pragma unroll
        for (int i = 0; i < 4; ++i) ue.q[i] = rp[i];
        float acc[NK];
#pragma unroll 1
        for (int k = 0; k < NK; ++k) {
            union { uint4 q[4]; h2 hh[16]; } ua;
            const uint4* ap = (const uint4*)(awh + k * 32 + h * 16);
#pragma unroll
            for (int i = 0; i < 4; ++i) ua.q[i] = ap[i];
            float a = 0.f;
#pragma unroll
            for (int i = 0; i < 16; ++i) a = fdot2(ue.hh[i], ua.hh[i], a);
            acc[k] = a;
        }
#pragma unroll
        for (int k = 0; k < NK; ++k) acc[k] += __shfl_xor(acc[k], 1);
        if (h == 0) {
#pragma unroll
            for (int k = 0; k < NK; ++k)
                att[k * Ssz + s] = fast_tanh(acc[k] + att_b[k]);
        }
    }
    __syncthreads();

    // ---- P2: softmax over s per k (waves 0..4); scores -> packed fp16 pairs ----
    if (w < NK) {
        const int k = w;
        float vals[4];
        float mx = -1e30f;
#pragma unroll
        for (int j = 0; j < 4; ++j) {
            int s = l + 64 * j;
            vals[j] = (s < Ssz) ? att[k * Ssz + s] : -1e30f;
            mx = fmaxf(mx, vals[j]);
        }
#pragma unroll
        for (int m = 32; m >= 1; m >>= 1) mx = fmaxf(mx, __shfl_xor(mx, m));
        float sum = 0.f;
#pragma unroll
        for (int j = 0; j < 4; ++j) {
            vals[j] = __expf(vals[j] - mx);
            sum += vals[j];
        }
#pragma unroll
        for (int m = 32; m >= 1; m >>= 1) sum += __shfl_xor(sum, m);
        float inv = 1.0f / sum;
#pragma unroll
        for (int j = 0; j < 4; ++j) {
            const int s = l + 64 * j;
            float scv = vals[j] * inv;
            float pnr = __shfl_xor(scv, 1);          // lane pair (s, s+1)
            if (s < Ssz && (l & 1) == 0)
                att5[s >> 1][k] = pk(scv, pnr);      // all-k packed per pair
        }
    }
    __syncthreads();   // att (fp32) dead; ovl becomes urph

    // ---- P3: user_rep; thread (c=tid&15 -> b64 d-frag, j=tid>>4 -> s-pair group) ----
    {
        const int c = tid & 15;          // d-halves [4c, 4c+4)
        const int j = tid >> 4;          // 0..31; pairs p = j + 32t
        h2 acc[NK][2];
#pragma unroll
        for (int k = 0; k < NK; ++k) {
            acc[k][0] = (h2){(half_t)0, (half_t)0};
            acc[k][1] = (h2){(half_t)0, (half_t)0};
        }
#pragma unroll
        for (int t = 0; t < 4; ++t) {
            const int p = j + 32 * t;
            if (p < 100) {
                const int s0 = 2 * p;
                union { uint2 q; h2 hh[2]; } e0, e1;
                e0.q = *(const uint2*)(embh + s0 * ROWH + c * 4);
                e1.q = *(const uint2*)(embh + (s0 + 1) * ROWH + c * 4);
                union { uint4 q; h2 hh[4]; } sq;     // k = 0..3 score pairs
                sq.q = *(const uint4*)(&att5[p][0]); // one b128
                h2 s4 = att5[p][4];                  // k = 4
#pragma unroll
                for (int k = 0; k < NK; ++k) {
                    h2 sp = (k < 4) ? sq.hh[k] : s4;
                    h2 sc0 = (h2){sp.x, sp.x};
                    h2 sc1 = (h2){sp.y, sp.y};
                    acc[k][0] += e0.hh[0] * sc0;
                    acc[k][1] += e0.hh[1] * sc0;
                    acc[k][0] += e1.hh[0] * sc1;
                    acc[k][1] += e1.hh[1] * sc1;
                }
            }
        }
        // reduce the wave's 4 j-groups (lane bits 4,5) -- 2 levels
#pragma unroll
        for (int k = 0; k < NK; ++k)
#pragma unroll
            for (int i = 0; i < 2; ++i) {
                acc[k][i] += shfl_xor_h2(acc[k][i], 16);
                acc[k][i] += shfl_xor_h2(acc[k][i], 32);
            }
        if (l < 16) {
#pragma unroll
            for (int k = 0; k < NK; ++k) {
                union { h2 a[2]; uint2 q; } uu;
                uu.a[0] = acc[k][0]; uu.a[1] = acc[k][1];
                *(uint2*)(&urph[w][k][l * 4]) = uu.q;
            }
        }
    }
    __syncthreads();

    // ---- P4: fold 8 wave-partials -> fp32 ur (320 threads) ----
    if (tid < NK * Dsz) {
        const int k = tid >> 6, d = tid & 63;
        float ssum = 0.f;
#pragma unroll
        for (int jj = 0; jj < 8; ++jj) ssum += (float)urph[jj][k][d];
        ur[k][d] = ssum;
    }
    __syncthreads();

    // ---- P5: W_user[j] = ur[g(j)] . W_g[r(j)] ----
    for (int j = w; j < 18; j += 8) {
        const float* Wp; int g, c0;
        if      (j < 2)  { g = 0; c0 = 0;  Wp = W0; }
        else if (j < 6)  { g = 1; c0 = 2;  Wp = W1; }
        else if (j < 10) { g = 2; c0 = 6;  Wp = W2; }
        else if (j < 12) { g = 3; c0 = 10; Wp = W3; }
        else             { g = 4; c0 = 12; Wp = W4; }
        float p = ur[g][l] * Wp[(j - c0) * Dsz + l];
#pragma unroll
        for (int m = 32; m >= 1; m >>= 1) p += __shfl_xor(p, m);
        if (l == 0) wu[j] = p;
    }
    __syncthreads();

    // ---- P6: per-group softmax -> logits; CE -> atomic loss ----
    if (w == 0) {
        float lossb = 0.f;
        if (l < NK) {
            const int LEN[5] = {2, 4, 4, 2, 6};
            const int C0[5]  = {0, 2, 6, 10, 12};
            const int g = l, c0 = C0[g], len = LEN[g];
            float* op = out_logit + (size_t)b * 18;
            const float* yp = y + (size_t)b * 18;
            float mx = -1e30f;
            for (int j = 0; j < len; ++j) mx = fmaxf(mx, wu[c0 + j]);
            float sum = 0.f;
            for (int j = 0; j < len; ++j) sum += __expf(wu[c0 + j] - mx);
            float inv = 1.0f / sum;
            float lse = mx + __logf(sum);
            for (int j = 0; j < len; ++j) {
                op[c0 + j] = __expf(wu[c0 + j] - mx) * inv;
                lossb += (lse - wu[c0 + j]) * yp[c0 + j];
            }
        }
#pragma unroll
        for (int m = 1; m <= 4; m <<= 1) lossb += __shfl_xor(lossb, m);
        if (l == 0) atomicAdd(loss_out, lossb * (1.0f / Bsz));
    }
}

extern "C" void kernel_launch(void* const* d_in, const int* in_sizes, int n_in,
                              void* d_out, int out_size, void* d_ws, size_t ws_size,
                              hipStream_t stream) {
    const int*   x   = (const int*)d_in[0];
    const float* y   = (const float*)d_in[1];
    const float* emb = (const float*)d_in[2];
    const float* aw  = (const float*)d_in[3];
    const float* ab  = (const float*)d_in[4];
    const float* W0  = (const float*)d_in[5];
    const float* W1  = (const float*)d_in[6];
    const float* W2  = (const float*)d_in[7];
    const float* W3  = (const float*)d_in[8];
    const float* W4  = (const float*)d_in[9];
    float* out  = (float*)d_out;
    float* loss = out + (size_t)Bsz * 18;

    zero_loss_kernel<<<1, 64, 0, stream>>>(loss);
    tan_kernel<<<Bsz, NT, 0, stream>>>(x, y, emb, aw, ab,
                                       W0, W1, W2, W3, W4, out, loss);
}